// Round 1
// baseline (227.547 us; speedup 1.0000x reference)
//
#include <hip/hip_runtime.h>
#include <hip/hip_bf16.h>

#define BATCH 128
#define DMEM 64
#define NMEM 4096
#define DMODEL 1024
#define S1 4            // stage1 N-splits
#define LDS_STRIDE 40   // bf16 elems per dim-row (80 B)

typedef __bf16 v8bf __attribute__((ext_vector_type(8)));
typedef __bf16 v2bf __attribute__((ext_vector_type(2)));
typedef float v4f __attribute__((ext_vector_type(4)));
typedef float v16f __attribute__((ext_vector_type(16)));

// ---------------------------------------------------------------------------
// Split-K fp32 GEMM, 64x64 tile, 4x4 accs/thread (FMA-bound, not LDS-bound):
//   dst[m0..+64][n0..+64] (+)= A[.][k0:k0+128] @ W[.][k0:k0+128]^T
// ATOMIC=0: plain store (each (ks,row,col) written once).
// ATOMIC=1: unsafeAtomicAdd into pre-initialized dst.
// ---------------------------------------------------------------------------
template <int ATOMIC>
__device__ __forceinline__ void gemm64(const float* __restrict__ A,
                                       const float* __restrict__ W,
                                       float* __restrict__ dst,
                                       int m0, int n0, int k0,
                                       float* smem) {
    float(*As)[36] = (float(*)[36])smem;
    float(*Ws)[36] = (float(*)[36])(smem + 64 * 36);
    const int t = threadIdx.x;
    const int lrow = t >> 2;        // 0..63
    const int lc8 = (t & 3) * 8;    // 0,8,16,24
    const int rp = t >> 4;          // 0..15
    const int cp = t & 15;          // 0..15

    float acc[4][4];
#pragma unroll
    for (int j = 0; j < 4; ++j)
#pragma unroll
        for (int i = 0; i < 4; ++i) acc[j][i] = 0.f;

    v4f av0 = *(const v4f*)&A[(size_t)(m0 + lrow) * DMODEL + k0 + lc8];
    v4f av1 = *(const v4f*)&A[(size_t)(m0 + lrow) * DMODEL + k0 + lc8 + 4];
    v4f wv0 = *(const v4f*)&W[(size_t)(n0 + lrow) * DMODEL + k0 + lc8];
    v4f wv1 = *(const v4f*)&W[(size_t)(n0 + lrow) * DMODEL + k0 + lc8 + 4];

    for (int c = 0; c < 4; ++c) {
        __syncthreads();
        *(v4f*)&As[lrow][lc8] = av0;
        *(v4f*)&As[lrow][lc8 + 4] = av1;
        *(v4f*)&Ws[lrow][lc8] = wv0;
        *(v4f*)&Ws[lrow][lc8 + 4] = wv1;
        __syncthreads();
        if (c + 1 < 4) {
            const int kc = k0 + (c + 1) * 32;
            av0 = *(const v4f*)&A[(size_t)(m0 + lrow) * DMODEL + kc + lc8];
            av1 = *(const v4f*)&A[(size_t)(m0 + lrow) * DMODEL + kc + lc8 + 4];
            wv0 = *(const v4f*)&W[(size_t)(n0 + lrow) * DMODEL + kc + lc8];
            wv1 = *(const v4f*)&W[(size_t)(n0 + lrow) * DMODEL + kc + lc8 + 4];
        }
#pragma unroll
        for (int kk = 0; kk < 32; kk += 4) {
            v4f a[4], b[4];
#pragma unroll
            for (int j = 0; j < 4; ++j) a[j] = *(v4f*)&As[rp + 16 * j][kk];
#pragma unroll
            for (int i = 0; i < 4; ++i) b[i] = *(v4f*)&Ws[cp + 16 * i][kk];
#pragma unroll
            for (int j = 0; j < 4; ++j)
#pragma unroll
                for (int i = 0; i < 4; ++i)
#pragma unroll
                    for (int q = 0; q < 4; ++q)
                        acc[j][i] = fmaf(a[j][q], b[i][q], acc[j][i]);
        }
    }
#pragma unroll
    for (int j = 0; j < 4; ++j)
#pragma unroll
        for (int i = 0; i < 4; ++i) {
            float* p = &dst[(size_t)(m0 + rp + 16 * j) * DMODEL + n0 + cp + 16 * i];
            if (ATOMIC)
                unsafeAtomicAdd(p, acc[j][i]);
            else
                *p = acc[j][i];
        }
}

// ---------------------------------------------------------------------------
// K1: blocks [0,512)    -> stage1 partials (32x32x16 bf16 MFMA, dbuf LDS,
//                          depth-2 register prefetch); S1=4 splits
//     blocks [512,768)  -> q-projection split-K(8) partials into qa_p
// stage1 output pmat is TRANSPOSED: pmat[s][b][e][d] (rows contiguous in d)
// ---------------------------------------------------------------------------
__global__ __launch_bounds__(256, 3) void k1(const float* __restrict__ mem,
                                             const float* __restrict__ addr,
                                             float* __restrict__ pmat,
                                             float* __restrict__ pnorm,
                                             const float* __restrict__ query,
                                             const float* __restrict__ Wq,
                                             float* __restrict__ qa_p) {
    __shared__ __align__(16) char smem[24576];
    const int bid = blockIdx.x;
    const int nst = BATCH * S1;  // 512

    if (bid >= nst) {
        const int b2 = bid - nst;            // 0..255
        const int m0 = (b2 & 1) * 64;
        const int n0 = ((b2 >> 1) & 15) * 64;
        const int ks = b2 >> 5;              // 0..7
        gemm64<0>(query, Wq, qa_p + (size_t)ks * BATCH * DMODEL,
                  m0, n0, ks * 128, (float*)smem);
        return;
    }

    float* norm_s = (float*)(smem + 20480);  // [16][64] floats

    const int t = threadIdx.x;
    const int b = bid & (BATCH - 1);
    const int s = bid >> 7;                  // 0..3
    const int slots_per = NMEM / S1;         // 1024
    const int chunks = slots_per >> 5;       // 32

    const int u = t & 15;
    const int v = t >> 4;
    const int d0 = u * 4;

    const int l = t & 63;
    const int wv = t >> 6;
    const int strip = wv >> 1;
    const int kh = wv & 1;
    const int lrow = l & 31;
    const int lh = l >> 5;

    const size_t mem_base = ((size_t)b * NMEM + (size_t)s * slots_per) * DMEM;
    const size_t addr_base = (size_t)s * slots_per * DMEM;
    const size_t so = (size_t)(2 * v) * DMEM + d0;

    v16f acc0, acc1;
#pragma unroll
    for (int r = 0; r < 16; ++r) { acc0[r] = 0.f; acc1[r] = 0.f; }
    float nacc[4] = {0.f, 0.f, 0.f, 0.f};

    // even/odd register sets -> prefetch distance of 2 chunks
    v4f mE0 = *(const v4f*)&mem[mem_base + so];
    v4f mE1 = *(const v4f*)&mem[mem_base + so + DMEM];
    v4f aE0 = *(const v4f*)&addr[addr_base + so];
    v4f aE1 = *(const v4f*)&addr[addr_base + so + DMEM];
    v4f mO0 = *(const v4f*)&mem[mem_base + 2048 + so];
    v4f mO1 = *(const v4f*)&mem[mem_base + 2048 + so + DMEM];
    v4f aO0 = *(const v4f*)&addr[addr_base + 2048 + so];
    v4f aO1 = *(const v4f*)&addr[addr_base + 2048 + so + DMEM];

    __bf16* kb0 = (__bf16*)smem;
    __bf16* mb0 = kb0 + 64 * LDS_STRIDE;
    __bf16* kb1 = (__bf16*)(smem + 10240);
    __bf16* mb1 = kb1 + 64 * LDS_STRIDE;
    const int cb = 16 * kh + 8 * lh;

    for (int cc = 0; cc < chunks; cc += 2) {
        // ---- even chunk ----
#pragma unroll
        for (int i = 0; i < 4; ++i) {
            float kf0 = fmaxf(mE0[i] + aE0[i], 0.f);
            float kf1 = fmaxf(mE1[i] + aE1[i], 0.f);
            nacc[i] += kf0 + kf1;
            v2bf kp; kp[0] = (__bf16)kf0; kp[1] = (__bf16)kf1;
            v2bf mp; mp[0] = (__bf16)mE0[i]; mp[1] = (__bf16)mE1[i];
            *(v2bf*)&kb0[(d0 + i) * LDS_STRIDE + 2 * v] = kp;
            *(v2bf*)&mb0[(d0 + i) * LDS_STRIDE + 2 * v] = mp;
        }
        if (cc + 2 < chunks) {
            const size_t coff = (size_t)(cc + 2) * 32 * DMEM;
            mE0 = *(const v4f*)&mem[mem_base + coff + so];
            mE1 = *(const v4f*)&mem[mem_base + coff + so + DMEM];
            aE0 = *(const v4f*)&addr[addr_base + coff + so];
            aE1 = *(const v4f*)&addr[addr_base + coff + so + DMEM];
        }
        __syncthreads();
        {
            v8bf af = *(v8bf*)&kb0[(32 * strip + lrow) * LDS_STRIDE + cb];
            v8bf b0 = *(v8bf*)&mb0[lrow * LDS_STRIDE + cb];
            v8bf b1 = *(v8bf*)&mb0[(32 + lrow) * LDS_STRIDE + cb];
            acc0 = __builtin_amdgcn_mfma_f32_32x32x16_bf16(af, b0, acc0, 0, 0, 0);
            acc1 = __builtin_amdgcn_mfma_f32_32x32x16_bf16(af, b1, acc1, 0, 0, 0);
        }
        // ---- odd chunk ----
#pragma unroll
        for (int i = 0; i < 4; ++i) {
            float kf0 = fmaxf(mO0[i] + aO0[i], 0.f);
            float kf1 = fmaxf(mO1[i] + aO1[i], 0.f);
            nacc[i] += kf0 + kf1;
            v2bf kp; kp[0] = (__bf16)kf0; kp[1] = (__bf16)kf1;
            v2bf mp; mp[0] = (__bf16)mO0[i]; mp[1] = (__bf16)mO1[i];
            *(v2bf*)&kb1[(d0 + i) * LDS_STRIDE + 2 * v] = kp;
            *(v2bf*)&mb1[(d0 + i) * LDS_STRIDE + 2 * v] = mp;
        }
        if (cc + 3 < chunks) {
            const size_t coff = (size_t)(cc + 3) * 32 * DMEM;
            mO0 = *(const v4f*)&mem[mem_base + coff + so];
            mO1 = *(const v4f*)&mem[mem_base + coff + so + DMEM];
            aO0 = *(const v4f*)&addr[addr_base + coff + so];
            aO1 = *(const v4f*)&addr[addr_base + coff + so + DMEM];
        }
        __syncthreads();
        {
            v8bf af = *(v8bf*)&kb1[(32 * strip + lrow) * LDS_STRIDE + cb];
            v8bf b0 = *(v8bf*)&mb1[lrow * LDS_STRIDE + cb];
            v8bf b1 = *(v8bf*)&mb1[(32 + lrow) * LDS_STRIDE + cb];
            acc0 = __builtin_amdgcn_mfma_f32_32x32x16_bf16(af, b0, acc0, 0, 0, 0);
            acc1 = __builtin_amdgcn_mfma_f32_32x32x16_bf16(af, b1, acc1, 0, 0, 0);
        }
    }

    __syncthreads();  // drain frag reads; reuse staging LDS
    float* red = (float*)smem;  // [64 e][stride 68] floats = 17408 B
#pragma unroll
    for (int i = 0; i < 4; ++i) norm_s[v * 64 + d0 + i] = nacc[i];
    if (kh == 1) {
#pragma unroll
        for (int r = 0; r < 16; ++r) {
            int row = (r & 3) + 8 * (r >> 2) + 4 * lh;
            int d = 32 * strip + row;
            red[lrow * 68 + d] = acc0[r];          // e=lrow
            red[(32 + lrow) * 68 + d] = acc1[r];   // e=32+lrow
        }
    }
    __syncthreads();
    if (kh == 0) {
#pragma unroll
        for (int r = 0; r < 16; ++r) {
            int row = (r & 3) + 8 * (r >> 2) + 4 * lh;
            int d = 32 * strip + row;
            red[lrow * 68 + d] += acc0[r];
            red[(32 + lrow) * 68 + d] += acc1[r];
        }
    }
    __syncthreads();
    // coalesced transposed write-out: pmat[s][b][e][d]
    {
        float* pm = pmat + ((size_t)s * BATCH + b) * 4096;
        const int e = t >> 2;
        const int ds = (t & 3) * 16;
#pragma unroll
        for (int j = 0; j < 4; ++j)
            *(v4f*)&pm[e * 64 + ds + 4 * j] = *(v4f*)&red[e * 68 + ds + 4 * j];
    }
    if (t < 64) {
        float ssum = 0.f;
#pragma unroll
        for (int g = 0; g < 16; ++g) ssum += norm_s[g * 64 + t];
        pnorm[((size_t)s * BATCH + b) * 64 + t] = ssum;
    }
}

// ---------------------------------------------------------------------------
// stage2: 512 blocks = (b, e-quarter). Reduces pmat/pnorm/qa partials, then
// attn[h][e] = (qa[h]·mat[e,:]) / (qa[h]·nrm + 1e-5). One output per thread.
// Also initializes out = bm (epilogue target for gemm_out's atomic splits).
// ---------------------------------------------------------------------------
__global__ __launch_bounds__(256) void stage2(const float* __restrict__ pmat,
                                              const float* __restrict__ pnorm,
                                              const float* __restrict__ qa_p,
                                              const float* __restrict__ bq,
                                              float* __restrict__ attn,
                                              const float* __restrict__ bm,
                                              float* __restrict__ out) {
    __shared__ float mat_s[16 * 68];
    __shared__ float qa_s[16 * 68];
    __shared__ float nrm_s[64];
    const int t = threadIdx.x;
    const int b = blockIdx.x >> 2;
    const int eq = blockIdx.x & 3;

    // bias-init of final output (512*256 threads == 128*1024 elements)
    out[(size_t)b * DMODEL + eq * 256 + t] = bm[eq * 256 + t];

    {   // matrix e-quarter: 1024 contiguous floats per split (transposed layout)
        const int i4 = t * 4;
        v4f acc = (v4f){0.f, 0.f, 0.f, 0.f};
#pragma unroll
        for (int s = 0; s < S1; ++s)
            acc += *(const v4f*)&pmat[((size_t)s * BATCH + b) * 4096 + eq * 1024 + i4];
        *(v4f*)&mat_s[(i4 >> 6) * 68 + (i4 & 63)] = acc;
    }
#pragma unroll
    for (int i = 0; i < 4; ++i) {  // qa reduce + bias + relu
        const int idx = t + 256 * i;
        float ssum = 0.f;
#pragma unroll
        for (int ks = 0; ks < 8; ++ks)
            ssum += qa_p[((size_t)ks * BATCH + b) * DMODEL + idx];
        qa_s[(idx >> 6) * 68 + (idx & 63)] = fmaxf(ssum + bq[idx], 0.f);
    }
    if (t < 64) {
        float ssum = 0.f;
#pragma unroll
        for (int s = 0; s < S1; ++s)
            ssum += pnorm[((size_t)s * BATCH + b) * 64 + t];
        nrm_s[t] = ssum;
    }
    __syncthreads();

    const int h = t >> 4;
    const int e = t & 15;
    float num = 0.f, den = 0.f;
#pragma unroll 8
    for (int d = 0; d < 64; ++d) {
        float q = qa_s[h * 68 + d];
        num = fmaf(q, mat_s[e * 68 + d], num);
        den = fmaf(q, nrm_s[d], den);
    }
    attn[(size_t)b * DMODEL + h * 64 + eq * 16 + e] = num / (den + 1e-5f);
}

// ---------------------------------------------------------------------------
// out-projection: split-K(8) 64x64 tiles, atomic accumulation into out
// (out was pre-initialized to bm by stage2).
// ---------------------------------------------------------------------------
__global__ __launch_bounds__(256) void gemm_out(const float* __restrict__ A,
                                                const float* __restrict__ W,
                                                float* __restrict__ out) {
    __shared__ __align__(16) float smem[2 * 64 * 36];
    gemm64<1>(A, W, out, blockIdx.x * 64, blockIdx.y * 64, blockIdx.z * 128,
              smem);
}

// ---------------------------------------------------------------------------
extern "C" void kernel_launch(void* const* d_in, const int* in_sizes, int n_in,
                              void* d_out, int out_size, void* d_ws, size_t ws_size,
                              hipStream_t stream) {
    const float* query     = (const float*)d_in[0];
    const float* addresses = (const float*)d_in[1];
    const float* memories  = (const float*)d_in[2];
    const float* Wq        = (const float*)d_in[3];
    const float* bq        = (const float*)d_in[4];
    const float* Wm        = (const float*)d_in[5];
    const float* bm        = (const float*)d_in[6];
    float* out = (float*)d_out;
    float* ws = (float*)d_ws;

    float* qa_p    = ws;                        // 8*128*1024   = 1048576 f
    float* attn_ws = qa_p + 1048576;            // 128*1024     =  131072 f
    float* pnorm   = attn_ws + 131072;          // 4*128*64     =   32768 f
    float* pmat    = pnorm + 32768;             // 4*128*4096   = 2097152 f

    k1<<<dim3(BATCH * S1 + 256), 256, 0, stream>>>(memories, addresses, pmat,
                                                   pnorm, query, Wq, qa_p);
    stage2<<<dim3(512), 256, 0, stream>>>(pmat, pnorm, qa_p, bq, attn_ws, bm, out);
    gemm_out<<<dim3(2, 16, 8), 256, 0, stream>>>(attn_ws, Wm, out);
}